// Round 1
// baseline (3342.998 us; speedup 1.0000x reference)
//
#include <hip/hip_runtime.h>
#include <math.h>

#define Bsz 1024
#define Npt 50
#define Hd 128
#define G4 512
#define Tt 50
#define NEGC 1000000000.0f
#define CTANH 10.0f
#define BN (Bsz*Npt)        /* 51200 */
#define BH (Bsz*Hd)         /* 131072 */

#define OFF_R 0
#define OFF_V 1024
#define OFF_LP 2048
#define OFF_A 2562048
#define OFF_C 2613248
#define OFF_P 2715648

__device__ __forceinline__ float fsig(float x) {
  return 1.0f / (1.0f + __expf(-x));
}

// accurate-enough tanh: exp2-based with poly branch near 0 (avoids cancellation)
__device__ __forceinline__ float ftanh(float x) {
  float x2 = x * x;
  float p = x * (1.0f + x2 * (-0.33333333f + x2 * 0.13333333f)); // x - x^3/3 + 2x^5/15
  float e = __expf(2.0f * x);
  float t = 1.0f - 2.0f * __builtin_amdgcn_rcpf(e + 1.0f);
  return (fabsf(x) < 0.1f) ? p : t;
}

__global__ __launch_bounds__(256) void k_init(const float* __restrict__ dinit,
                                              float* __restrict__ mask,
                                              float* __restrict__ h0,
                                              float* __restrict__ c0,
                                              float* __restrict__ dec0) {
  int i = blockIdx.x * 256 + threadIdx.x;
  if (i < BN) mask[i] = 0.0f;
  if (i < BH) {
    h0[i] = 0.0f;
    c0[i] = 0.0f;
    dec0[i] = dinit[i & 127];
  }
}

// context = ip @ W_emb + b_emb (K=2);  e_g = ctx @ Wref_g; e_p = ctx @ Wref_p
__global__ __launch_bounds__(256) void k_ctx_e(const float* __restrict__ ip,
                                               const float* __restrict__ Wemb,
                                               const float* __restrict__ bemb,
                                               const float* __restrict__ Wrg,
                                               const float* __restrict__ Wrp,
                                               float* __restrict__ eg,
                                               float* __restrict__ ep) {
  __shared__ __align__(16) float ctx[32][128];
  int t = threadIdx.x;
  int row0 = blockIdx.x * 32;
  #pragma unroll
  for (int i = 0; i < 16; ++i) {
    int f = t + i * 256;
    int r = f >> 7, hh = f & 127;
    float p0 = ip[(size_t)(row0 + r) * 2 + 0];
    float p1 = ip[(size_t)(row0 + r) * 2 + 1];
    ctx[r][hh] = p0 * Wemb[hh] + p1 * Wemb[Hd + hh] + bemb[hh];
  }
  __syncthreads();
  int tc = t & 127, th = t >> 7;
  float ag[16], ap[16];
  #pragma unroll
  for (int i = 0; i < 16; ++i) { ag[i] = 0.f; ap[i] = 0.f; }
  for (int k = 0; k < 128; k += 4) {
    float wg0 = Wrg[(k + 0) * Hd + tc], wg1 = Wrg[(k + 1) * Hd + tc];
    float wg2 = Wrg[(k + 2) * Hd + tc], wg3 = Wrg[(k + 3) * Hd + tc];
    float wp0 = Wrp[(k + 0) * Hd + tc], wp1 = Wrp[(k + 1) * Hd + tc];
    float wp2 = Wrp[(k + 2) * Hd + tc], wp3 = Wrp[(k + 3) * Hd + tc];
    #pragma unroll
    for (int i = 0; i < 16; ++i) {
      float4 cv = *(const float4*)&ctx[th * 16 + i][k];
      ag[i] += cv.x * wg0 + cv.y * wg1 + cv.z * wg2 + cv.w * wg3;
      ap[i] += cv.x * wp0 + cv.y * wp1 + cv.z * wp2 + cv.w * wp3;
    }
  }
  #pragma unroll
  for (int i = 0; i < 16; ++i) {
    size_t r = (size_t)(row0 + th * 16 + i);
    eg[r * Hd + tc] = ag[i];
    ep[r * Hd + tc] = ap[i];
  }
}

// gates = x @ Wi + h @ Wh + b  ; 8 batch rows per block, 256 cols per block
__global__ __launch_bounds__(256) void k_gates(const float* __restrict__ x,
                                               const float* __restrict__ h,
                                               const float* __restrict__ Wi,
                                               const float* __restrict__ Wh,
                                               const float* __restrict__ bl,
                                               float* __restrict__ gates) {
  int bg = blockIdx.x >> 1;
  int c = (blockIdx.x & 1) * 256 + threadIdx.x;
  int b0 = bg * 8;
  float bias = bl[c];
  float acc[8];
  #pragma unroll
  for (int i = 0; i < 8; ++i) acc[i] = bias;
  const float* xb = x + (size_t)b0 * Hd;
  const float* hb = h + (size_t)b0 * Hd;
  for (int k = 0; k < 128; k += 4) {
    #pragma unroll
    for (int kk = 0; kk < 4; ++kk) {
      float wi = Wi[(size_t)(k + kk) * G4 + c];
      float wh = Wh[(size_t)(k + kk) * G4 + c];
      #pragma unroll
      for (int i = 0; i < 8; ++i) {
        acc[i] += xb[i * Hd + k + kk] * wi + hb[i * Hd + k + kk] * wh;
      }
    }
  }
  #pragma unroll
  for (int i = 0; i < 8; ++i) gates[(size_t)(b0 + i) * G4 + c] = acc[i];
}

// fused: LSTM cell, q-proj, glimpse attention, Wq_p proj, pointer attention,
// log_softmax/softmax/argmax, outputs, mask update, dec_next.  2 batch rows/block.
__global__ __launch_bounds__(256) void k_attn(const float* __restrict__ eg,
                                              const float* __restrict__ epm,
                                              const float* __restrict__ gates,
                                              const float* __restrict__ c_in,
                                              float* __restrict__ h_out,
                                              float* __restrict__ c_out,
                                              float* __restrict__ mask,
                                              const float* __restrict__ Wqg,
                                              const float* __restrict__ vg,
                                              const float* __restrict__ Wqp,
                                              const float* __restrict__ vp,
                                              const float* __restrict__ ip,
                                              const float* __restrict__ Wemb,
                                              const float* __restrict__ bemb,
                                              float* __restrict__ dec_out,
                                              float* out, int step) {
  __shared__ __align__(16) float es[2 * Npt * Hd];   // 51.2 KB, e_g then e_p
  __shared__ __align__(16) float h2s[2][Hd];
  __shared__ __align__(16) float qs[2][Hd];
  __shared__ __align__(16) float gs[2][Hd];
  __shared__ __align__(16) float gps[2][Hd];
  __shared__ float us[2][64];
  __shared__ float ps[2][64];
  __shared__ float ms[2][Npt];
  int t = threadIdx.x;
  int blk = blockIdx.x;
  int w = t >> 6, lane = t & 63;

  // ---- P0: stage e_g, mask; LSTM cell from gates ----
  {
    const float4* src = (const float4*)(eg + (size_t)blk * 2 * Npt * Hd);
    float4* dst = (float4*)es;
    for (int i = t; i < 2 * Npt * Hd / 4; i += 256) dst[i] = src[i];
    if (t < 2 * Npt) ((float*)ms)[t] = mask[(size_t)blk * 2 * Npt + t];
    int bi = t >> 7, j = t & 127;
    size_t gb = (size_t)(blk * 2 + bi);
    float gi = gates[gb * G4 + j];
    float gf = gates[gb * G4 + 128 + j];
    float gg = gates[gb * G4 + 256 + j];
    float go = gates[gb * G4 + 384 + j];
    float cc = c_in[gb * Hd + j];
    float c2 = fsig(gf) * cc + fsig(gi) * ftanh(gg);
    float h2 = fsig(go) * ftanh(c2);
    c_out[gb * Hd + j] = c2;
    h_out[gb * Hd + j] = h2;
    h2s[bi][j] = h2;
  }
  __syncthreads();
  // ---- P1: q = h2 @ Wq_g ----
  {
    int bi = t >> 7, hh = t & 127;
    float a = 0.f;
    for (int k = 0; k < 128; k += 4) {
      float4 hv = *(const float4*)&h2s[bi][k];
      a += hv.x * Wqg[(k + 0) * Hd + hh] + hv.y * Wqg[(k + 1) * Hd + hh]
         + hv.z * Wqg[(k + 2) * Hd + hh] + hv.w * Wqg[(k + 3) * Hd + hh];
    }
    qs[bi][hh] = a;
  }
  __syncthreads();
  // ---- P2: u_n = v_g . tanh(e_g + q) - NEG*mask ----
  {
    int bi = w & 1;
    int n0 = (w >> 1) * 25;
    float2 v2 = *(const float2*)&vg[lane * 2];
    float2 q2 = *(const float2*)&qs[bi][lane * 2];
    for (int i = 0; i < 25; ++i) {
      int n = n0 + i;
      const float* er = es + bi * Npt * Hd + n * Hd;
      float2 ev = *(const float2*)&er[lane * 2];
      float s = v2.x * ftanh(ev.x + q2.x) + v2.y * ftanh(ev.y + q2.y);
      #pragma unroll
      for (int off = 32; off >= 1; off >>= 1) s += __shfl_xor(s, off, 64);
      if (lane == 0) us[bi][n] = s - NEGC * ms[bi][n];
    }
  }
  __syncthreads();
  // ---- P3: softmax(u) -> p ----
  if (w < 2) {
    int bi = w;
    float x = (lane < Npt) ? us[bi][lane] : -INFINITY;
    float m = x;
    #pragma unroll
    for (int off = 32; off >= 1; off >>= 1) m = fmaxf(m, __shfl_xor(m, off, 64));
    float e = __expf(x - m);
    float ssum = e;
    #pragma unroll
    for (int off = 32; off >= 1; off >>= 1) ssum += __shfl_xor(ssum, off, 64);
    ps[bi][lane] = (lane < Npt) ? (e / ssum) : 0.f;
  }
  __syncthreads();
  // ---- P4: g = p @ e_g ----
  {
    int bi = t >> 7, hh = t & 127;
    float a = 0.f;
    for (int n = 0; n < Npt; ++n) a += ps[bi][n] * es[bi * Npt * Hd + n * Hd + hh];
    gs[bi][hh] = a;
  }
  __syncthreads();
  // ---- P5: gp = g @ Wq_p ----
  {
    int bi = t >> 7, hh = t & 127;
    float a = 0.f;
    for (int k = 0; k < 128; k += 4) {
      float4 gv = *(const float4*)&gs[bi][k];
      a += gv.x * Wqp[(k + 0) * Hd + hh] + gv.y * Wqp[(k + 1) * Hd + hh]
         + gv.z * Wqp[(k + 2) * Hd + hh] + gv.w * Wqp[(k + 3) * Hd + hh];
    }
    gps[bi][hh] = a;
  }
  // ---- P6: stage e_p over es (P4 readers are past the P4->P5 barrier) ----
  {
    const float4* src = (const float4*)(epm + (size_t)blk * 2 * Npt * Hd);
    float4* dst = (float4*)es;
    for (int i = t; i < 2 * Npt * Hd / 4; i += 256) dst[i] = src[i];
  }
  __syncthreads();
  // ---- P7: logit_n = C*tanh(v_p . tanh(e_p + gp)) - NEG*mask ----
  {
    int bi = w & 1;
    int n0 = (w >> 1) * 25;
    float2 v2 = *(const float2*)&vp[lane * 2];
    float2 q2 = *(const float2*)&gps[bi][lane * 2];
    for (int i = 0; i < 25; ++i) {
      int n = n0 + i;
      const float* er = es + bi * Npt * Hd + n * Hd;
      float2 ev = *(const float2*)&er[lane * 2];
      float s = v2.x * ftanh(ev.x + q2.x) + v2.y * ftanh(ev.y + q2.y);
      #pragma unroll
      for (int off = 32; off >= 1; off >>= 1) s += __shfl_xor(s, off, 64);
      if (lane == 0) us[bi][n] = CTANH * ftanh(s) - NEGC * ms[bi][n];
    }
  }
  __syncthreads();
  // ---- P8: log_softmax / softmax / argmax / outputs / mask / dec_next ----
  if (w < 2) {
    int bi = w;
    int b = blk * 2 + bi;
    float x = (lane < Npt) ? us[bi][lane] : -INFINITY;
    float m = x;
    #pragma unroll
    for (int off = 32; off >= 1; off >>= 1) m = fmaxf(m, __shfl_xor(m, off, 64));
    float sh = x - m;
    float e = __expf(sh);
    float ssum = e;
    #pragma unroll
    for (int off = 32; off >= 1; off >>= 1) ssum += __shfl_xor(ssum, off, 64);
    float ls = __logf(ssum);
    float prob = e / ssum;
    float lp = sh - ls;
    if (lane < Npt) {
      out[OFF_LP + ((size_t)b * Tt + step) * Npt + lane] = lp;
      out[OFF_P + ((size_t)b * Tt + step) * Npt + lane] = prob;
    }
    float pv = (lane < Npt) ? prob : -1.f;
    int idx = lane;
    #pragma unroll
    for (int off = 32; off >= 1; off >>= 1) {
      float po = __shfl_xor(pv, off, 64);
      int io = __shfl_xor(idx, off, 64);
      if (po > pv || (po == pv && io < idx)) { pv = po; idx = io; }
    }
    int a = idx;
    float p0 = ip[((size_t)b * Npt + a) * 2 + 0];
    float p1 = ip[((size_t)b * Npt + a) * 2 + 1];
    if (lane == 0) {
      out[OFF_A + (size_t)b * Tt + step] = (float)a;
      out[OFF_C + ((size_t)b * Tt + step) * 2 + 0] = p0;
      out[OFF_C + ((size_t)b * Tt + step) * 2 + 1] = p1;
      mask[(size_t)b * Npt + a] = 1.0f;
    }
    dec_out[(size_t)b * Hd + lane]      = p0 * Wemb[lane]      + p1 * Wemb[Hd + lane]      + bemb[lane];
    dec_out[(size_t)b * Hd + lane + 64] = p0 * Wemb[lane + 64] + p1 * Wemb[Hd + lane + 64] + bemb[lane + 64];
  }
}

// C[M x 128] = act(A[M x 128] @ W[128 x 128] + bias), 8 rows/block
__global__ __launch_bounds__(256) void k_mm128(const float* __restrict__ A,
                                               const float* __restrict__ W,
                                               const float* __restrict__ bias,
                                               float* __restrict__ C, int relu) {
  __shared__ __align__(16) float As[8][128];
  int t = threadIdx.x;
  int r0 = blockIdx.x * 8;
  ((float4*)As)[t] = ((const float4*)(A + (size_t)r0 * Hd))[t];
  __syncthreads();
  int hh = t & 127, rg = t >> 7;
  float acc[4] = {0.f, 0.f, 0.f, 0.f};
  for (int k = 0; k < 128; k += 4) {
    float w0 = W[(k + 0) * Hd + hh], w1 = W[(k + 1) * Hd + hh];
    float w2 = W[(k + 2) * Hd + hh], w3 = W[(k + 3) * Hd + hh];
    #pragma unroll
    for (int i = 0; i < 4; ++i) {
      float4 av = *(const float4*)&As[rg * 4 + i][k];
      acc[i] += av.x * w0 + av.y * w1 + av.z * w2 + av.w * w3;
    }
  }
  float bv = bias ? bias[hh] : 0.f;
  #pragma unroll
  for (int i = 0; i < 4; ++i) {
    float o = acc[i] + bv;
    if (relu) o = fmaxf(o, 0.f);
    C[(size_t)(r0 + rg * 4 + i) * Hd + hh] = o;
  }
}

// v = relu-chain result dot W2 + b2 ; R = tour length from coords (in out buffer)
__global__ __launch_bounds__(256) void k_final(const float* __restrict__ t2,
                                               const float* __restrict__ W2,
                                               const float* __restrict__ b2,
                                               float* out) {
  int w = threadIdx.x >> 6, lane = threadIdx.x & 63;
  int b = blockIdx.x * 4 + w;
  float s = t2[(size_t)b * Hd + lane] * W2[lane] + t2[(size_t)b * Hd + lane + 64] * W2[lane + 64];
  #pragma unroll
  for (int off = 32; off >= 1; off >>= 1) s += __shfl_xor(s, off, 64);
  if (lane == 0) out[OFF_V + b] = s + b2[0];

  const float* cbp = out + OFF_C + (size_t)b * Tt * 2;
  float r = 0.f;
  if (lane < Tt - 1) {
    float dx = cbp[(lane + 1) * 2] - cbp[lane * 2];
    float dy = cbp[(lane + 1) * 2 + 1] - cbp[lane * 2 + 1];
    r = sqrtf(dx * dx + dy * dy + 1e-10f);
  } else if (lane == Tt - 1) {
    float dx = cbp[0] - cbp[(Tt - 1) * 2];
    float dy = cbp[1] - cbp[(Tt - 1) * 2 + 1];
    r = sqrtf(dx * dx + dy * dy + 1e-10f);
  }
  #pragma unroll
  for (int off = 32; off >= 1; off >>= 1) r += __shfl_xor(r, off, 64);
  if (lane == 0) out[OFF_R + b] = r;
}

extern "C" void kernel_launch(void* const* d_in, const int* in_sizes, int n_in,
                              void* d_out, int out_size, void* d_ws, size_t ws_size,
                              hipStream_t stream) {
  (void)in_sizes; (void)n_in; (void)out_size; (void)ws_size;
  const float* ip    = (const float*)d_in[0];
  const float* Wemb  = (const float*)d_in[1];
  const float* bemb  = (const float*)d_in[2];
  const float* dinit = (const float*)d_in[3];
  const float* Wi    = (const float*)d_in[4];
  const float* Wh    = (const float*)d_in[5];
  const float* bl    = (const float*)d_in[6];
  const float* Wqg   = (const float*)d_in[7];
  const float* Wrg   = (const float*)d_in[8];
  const float* vg    = (const float*)d_in[9];
  const float* Wqp   = (const float*)d_in[10];
  const float* Wrp   = (const float*)d_in[11];
  const float* vp    = (const float*)d_in[12];
  // d_in[13..16], d_in[18] are dead (critic N=1 softmax == 1 => hy = e_c)
  const float* Wrc   = (const float*)d_in[17];
  const float* W1    = (const float*)d_in[19];
  const float* b1    = (const float*)d_in[20];
  const float* W2    = (const float*)d_in[21];
  const float* b2    = (const float*)d_in[22];
  float* out = (float*)d_out;
  float* ws  = (float*)d_ws;

  float* eg    = ws;
  float* ep    = eg + (size_t)BN * Hd;
  float* mask  = ep + (size_t)BN * Hd;
  float* hb    = mask + BN;            // 2*BH
  float* cbuf  = hb + 2 * BH;          // 2*BH
  float* db    = cbuf + 2 * BH;        // 2*BH
  float* gates = db + 2 * BH;          // B*G4
  float* ec    = gates + (size_t)Bsz * G4;
  float* t2b   = ec + BH;

  k_init<<<512, 256, 0, stream>>>(dinit, mask, hb, cbuf, db);
  k_ctx_e<<<1600, 256, 0, stream>>>(ip, Wemb, bemb, Wrg, Wrp, eg, ep);

  for (int t = 0; t < Tt; ++t) {
    float* hin  = hb   + (size_t)(t & 1) * BH;
    float* hout = hb   + (size_t)((t + 1) & 1) * BH;
    float* cin  = cbuf + (size_t)(t & 1) * BH;
    float* cout = cbuf + (size_t)((t + 1) & 1) * BH;
    float* din  = db   + (size_t)(t & 1) * BH;
    float* dnx  = db   + (size_t)((t + 1) & 1) * BH;
    k_gates<<<256, 256, 0, stream>>>(din, hin, Wi, Wh, bl, gates);
    k_attn<<<512, 256, 0, stream>>>(eg, ep, gates, cin, hout, cout, mask,
                                    Wqg, vg, Wqp, vp, ip, Wemb, bemb, dnx, out, t);
  }
  // dec_last is db + 0 after the loop (T even)
  k_mm128<<<128, 256, 0, stream>>>(db, Wrc, nullptr, ec, 0);
  k_mm128<<<128, 256, 0, stream>>>(ec, W1, b1, t2b, 1);
  k_final<<<256, 256, 0, stream>>>(t2b, W2, b2, out);
}